// Round 8
// baseline (151.027 us; speedup 1.0000x reference)
//
#include <hip/hip_runtime.h>
#include <hip/hip_bf16.h>

typedef float f32x4 __attribute__((ext_vector_type(4)));
typedef int   i32x4 __attribute__((ext_vector_type(4)));
typedef unsigned short u16;
typedef unsigned int   u32;
typedef u16 u16x4 __attribute__((ext_vector_type(4)));
typedef u16 u16x8 __attribute__((ext_vector_type(8)));

#define D4  32  // D=128 floats = 32 float4 per row; also 32 u16x4 per row

__device__ __forceinline__ float softplus_f(float r) {
    return (r > 20.0f) ? r : __logf(1.0f + __expf(r));
}
__device__ __forceinline__ float clip10(float e) {
    return fminf(fmaxf(e, -10.0f), 10.0f);
}
__device__ __forceinline__ u16 f32_to_bf16_rne(float f) {
    u32 b = __float_as_uint(f);
    b += 0x7FFFu + ((b >> 16) & 1u);   // round-to-nearest-even
    return (u16)(b >> 16);
}
__device__ __forceinline__ float bf16_to_f32(u16 h) {
    return __uint_as_float(((u32)h) << 16);
}

// Pass 1: tab[i] = bf16( mu[i] + softplus(rho[i]) * clip(eps[i]) ), 8 elems/thread.
__global__ __launch_bounds__(256) void sample_table_bf16_kernel(
    const f32x4* __restrict__ mu,
    const f32x4* __restrict__ rho,
    const f32x4* __restrict__ eps,
    u16x4* __restrict__ tab,
    long n4)
{
    long t  = (long)blockIdx.x * blockDim.x + threadIdx.x;
    long j0 = t * 2, j1 = j0 + 1;
    if (j0 >= n4) return;

    f32x4 m0 = __builtin_nontemporal_load(&mu[j0]);
    f32x4 r0 = __builtin_nontemporal_load(&rho[j0]);
    f32x4 e0 = __builtin_nontemporal_load(&eps[j0]);

    u16x4 o0;
    o0.x = f32_to_bf16_rne(m0.x + softplus_f(r0.x) * clip10(e0.x));
    o0.y = f32_to_bf16_rne(m0.y + softplus_f(r0.y) * clip10(e0.y));
    o0.z = f32_to_bf16_rne(m0.z + softplus_f(r0.z) * clip10(e0.z));
    o0.w = f32_to_bf16_rne(m0.w + softplus_f(r0.w) * clip10(e0.w));

    if (j1 < n4) {
        f32x4 m1 = __builtin_nontemporal_load(&mu[j1]);
        f32x4 r1 = __builtin_nontemporal_load(&rho[j1]);
        f32x4 e1 = __builtin_nontemporal_load(&eps[j1]);
        u16x8 o;
        o[0] = o0.x; o[1] = o0.y; o[2] = o0.z; o[3] = o0.w;
        o[4] = f32_to_bf16_rne(m1.x + softplus_f(r1.x) * clip10(e1.x));
        o[5] = f32_to_bf16_rne(m1.y + softplus_f(r1.y) * clip10(e1.y));
        o[6] = f32_to_bf16_rne(m1.z + softplus_f(r1.z) * clip10(e1.z));
        o[7] = f32_to_bf16_rne(m1.w + softplus_f(r1.w) * clip10(e1.w));
        *(u16x8*)&tab[j0] = o;           // one 16 B store
    } else {
        tab[j0] = o0;
    }
}

// Pass 2: out[row,:] = f32(tab[x[row],:]).
// 32 lanes per row (8 B u16x4 gather per lane, 512 B contiguous store
// per row). Each thread owns 4 CONSECUTIVE rows (4s..4s+3): the wave's
// 4 store instructions cover one contiguous 4 KB output span (DRAM page
// locality, fill-like), and the 4 indices come from one 16 B load.
__global__ __launch_bounds__(256) void gather_bf16_kernel(
    const int* __restrict__ x,
    const u16x4* __restrict__ tab,
    f32x4* __restrict__ out,
    int n_rows, int n_slots)
{
    int g    = blockIdx.x * blockDim.x + threadIdx.x;
    int slot = g >> 5;        // 32 lanes per slot (slot = 4 rows)
    int lane = g & 31;
    if (slot >= n_slots) return;

    long r0 = (long)slot * 4;
    int v0, v1, v2, v3;
    if (r0 + 3 < (long)n_rows) {
        i32x4 v = __builtin_nontemporal_load((const i32x4*)(x + r0));
        v0 = v.x; v1 = v.y; v2 = v.z; v3 = v.w;
    } else {
        v0 = x[r0];
        v1 = (r0 + 1 < n_rows) ? x[r0 + 1] : v0;
        v2 = (r0 + 2 < n_rows) ? x[r0 + 2] : v0;
        v3 = (r0 + 3 < n_rows) ? x[r0 + 3] : v0;
    }

    u16x4 t0 = tab[(long)v0 * D4 + lane];   // 4 independent gather chains
    u16x4 t1 = tab[(long)v1 * D4 + lane];
    u16x4 t2 = tab[(long)v2 * D4 + lane];
    u16x4 t3 = tab[(long)v3 * D4 + lane];

    #define EMIT(tk, rk)                                                     \
    {                                                                        \
        f32x4 o;                                                             \
        o.x = bf16_to_f32(tk.x); o.y = bf16_to_f32(tk.y);                    \
        o.z = bf16_to_f32(tk.z); o.w = bf16_to_f32(tk.w);                    \
        __builtin_nontemporal_store(o, &out[(rk) * D4 + lane]);              \
    }

    EMIT(t0, r0);
    if (r0 + 1 < n_rows) EMIT(t1, r0 + 1);
    if (r0 + 2 < n_rows) EMIT(t2, r0 + 2);
    if (r0 + 3 < n_rows) EMIT(t3, r0 + 3);
    #undef EMIT
}

// Fallback (ws too small): fused f32 kernel.
__global__ __launch_bounds__(256) void fused_kernel(
    const int* __restrict__ x,
    const f32x4* __restrict__ mu,
    const f32x4* __restrict__ rho,
    const f32x4* __restrict__ eps,
    f32x4* __restrict__ out,
    int n_rows)
{
    int tid  = blockIdx.x * blockDim.x + threadIdx.x;
    int row  = tid >> 5;
    int lane = tid & 31;
    if (row >= n_rows) return;
    long src = (long)x[row] * D4 + lane;
    f32x4 m = mu[src], r = rho[src], e = eps[src];
    f32x4 o;
    o.x = m.x + softplus_f(r.x) * clip10(e.x);
    o.y = m.y + softplus_f(r.y) * clip10(e.y);
    o.z = m.z + softplus_f(r.z) * clip10(e.z);
    o.w = m.w + softplus_f(r.w) * clip10(e.w);
    out[(long)row * D4 + lane] = o;
}

extern "C" void kernel_launch(void* const* d_in, const int* in_sizes, int n_in,
                              void* d_out, int out_size, void* d_ws, size_t ws_size,
                              hipStream_t stream)
{
    const int*   x   = (const int*)  d_in[0];
    const f32x4* mu  = (const f32x4*)d_in[1];
    const f32x4* rho = (const f32x4*)d_in[2];
    const f32x4* eps = (const f32x4*)d_in[3];
    f32x4* out = (f32x4*)d_out;

    int  n_rows      = in_sizes[0];        // B*L
    long table_elems = (long)in_sizes[1];  // V*D
    size_t table_bytes_bf16 = (size_t)table_elems * sizeof(u16);
    const int block = 256;

    if (ws_size >= table_bytes_bf16) {
        long n4 = table_elems / 4;

        long threads1 = (n4 + 1) / 2;                         // 2 float4 per thread
        int grid1 = (int)((threads1 + block - 1) / block);
        sample_table_bf16_kernel<<<grid1, block, 0, stream>>>(
            mu, rho, eps, (u16x4*)d_ws, n4);

        int n_slots = (n_rows + 3) / 4;                       // 4 consecutive rows/thread
        long threads2 = (long)n_slots * 32;                   // 32 lanes per slot
        int grid2 = (int)((threads2 + block - 1) / block);
        gather_bf16_kernel<<<grid2, block, 0, stream>>>(
            x, (const u16x4*)d_ws, out, n_rows, n_slots);
    } else {
        long threads = (long)n_rows * 32;
        int grid = (int)((threads + block - 1) / block);
        fused_kernel<<<grid, block, 0, stream>>>(x, mu, rho, eps, out, n_rows);
    }
}

// Round 9
// 139.474 us; speedup vs baseline: 1.0828x; 1.0828x over previous
//
#include <hip/hip_runtime.h>
#include <hip/hip_bf16.h>

typedef float f32x2 __attribute__((ext_vector_type(2)));
typedef float f32x4 __attribute__((ext_vector_type(4)));
typedef unsigned short u16;
typedef unsigned int   u32;
typedef u16 u16x4 __attribute__((ext_vector_type(4)));
typedef u16 u16x8 __attribute__((ext_vector_type(8)));

#define D4  32   // D=128 floats = 32 float4 per row
#define NXCD 8

__device__ __forceinline__ float softplus_f(float r) {
    return (r > 20.0f) ? r : __logf(1.0f + __expf(r));
}
__device__ __forceinline__ float clip10(float e) {
    return fminf(fmaxf(e, -10.0f), 10.0f);
}
__device__ __forceinline__ u16 f32_to_bf16_rne(float f) {
    u32 b = __float_as_uint(f);
    b += 0x7FFFu + ((b >> 16) & 1u);   // round-to-nearest-even
    return (u16)(b >> 16);
}
__device__ __forceinline__ float bf16_to_f32(u16 h) {
    return __uint_as_float(((u32)h) << 16);
}

// Pass 1: tab[i] = bf16( mu[i] + softplus(rho[i]) * clip(eps[i]) ), 8 elems/thread.
__global__ __launch_bounds__(256) void sample_table_bf16_kernel(
    const f32x4* __restrict__ mu,
    const f32x4* __restrict__ rho,
    const f32x4* __restrict__ eps,
    u16x4* __restrict__ tab,
    long n4)
{
    long t  = (long)blockIdx.x * blockDim.x + threadIdx.x;
    long j0 = t * 2, j1 = j0 + 1;
    if (j0 >= n4) return;

    f32x4 m0 = __builtin_nontemporal_load(&mu[j0]);
    f32x4 r0 = __builtin_nontemporal_load(&rho[j0]);
    f32x4 e0 = __builtin_nontemporal_load(&eps[j0]);

    u16x4 o0;
    o0.x = f32_to_bf16_rne(m0.x + softplus_f(r0.x) * clip10(e0.x));
    o0.y = f32_to_bf16_rne(m0.y + softplus_f(r0.y) * clip10(e0.y));
    o0.z = f32_to_bf16_rne(m0.z + softplus_f(r0.z) * clip10(e0.z));
    o0.w = f32_to_bf16_rne(m0.w + softplus_f(r0.w) * clip10(e0.w));

    if (j1 < n4) {
        f32x4 m1 = __builtin_nontemporal_load(&mu[j1]);
        f32x4 r1 = __builtin_nontemporal_load(&rho[j1]);
        f32x4 e1 = __builtin_nontemporal_load(&eps[j1]);
        u16x8 o;
        o[0] = o0.x; o[1] = o0.y; o[2] = o0.z; o[3] = o0.w;
        o[4] = f32_to_bf16_rne(m1.x + softplus_f(r1.x) * clip10(e1.x));
        o[5] = f32_to_bf16_rne(m1.y + softplus_f(r1.y) * clip10(e1.y));
        o[6] = f32_to_bf16_rne(m1.z + softplus_f(r1.z) * clip10(e1.z));
        o[7] = f32_to_bf16_rne(m1.w + softplus_f(r1.w) * clip10(e1.w));
        *(u16x8*)&tab[j0] = o;           // one 16 B store
    } else {
        tab[j0] = o0;
    }
}

// Pass 2, XCD-sliced: blockIdx%8 selects a vocab slice (12500 rows = 3.2 MB,
// fits one XCD's 4 MB L2; blockIdx%8 round-robins to XCDs). Each block scans
// a chunk of x with a 64-lane ballot and gathers only rows in its slice, so
// each table row crosses the fabric once and then hits the local L2.
// Row read: 64 lanes x 4 B (u32 = 2 bf16) = 256 B = one bf16 row.
// Row write: 64 lanes x 8 B (f32x2) = 512 B contiguous, nontemporal.
__global__ __launch_bounds__(256) void gather_sliced_kernel(
    const int* __restrict__ x,
    const u32* __restrict__ tab,   // bf16 table viewed as u32 pairs: 64 per row
    f32x2* __restrict__ out,       // f32 rows: 64 f32x2 per row
    int n_rows, int vslice, int chunk)
{
    int bucket  = blockIdx.x & (NXCD - 1);
    int chunkid = blockIdx.x >> 3;
    int lo = bucket * vslice;
    int hi = lo + vslice;

    long base = (long)chunkid * chunk;
    long end  = base + chunk;
    if (end > n_rows) end = n_rows;

    int wid  = threadIdx.x >> 6;   // 4 waves per block
    int lane = threadIdx.x & 63;

    for (long r = base + (long)wid * 64; r < end; r += 256) {
        long rr = r + lane;
        int  v  = (rr < end) ? x[rr] : -1;
        bool mine = (v >= lo) & (v < hi);
        unsigned long long mask = __ballot(mine);
        while (mask) {
            int bit = __ffsll((long long)mask) - 1;
            mask &= mask - 1;
            int  vv   = __shfl(v, bit);     // vocab row (wave-uniform)
            long orow = r + bit;            // output row
            u32 w = tab[(long)vv * 64 + lane];   // L2-resident slice
            f32x2 f;
            f.x = bf16_to_f32((u16)(w & 0xffffu));
            f.y = bf16_to_f32((u16)(w >> 16));
            __builtin_nontemporal_store(f, &out[orow * 64 + lane]);
        }
    }
}

// Fallback (ws too small): fused f32 kernel.
__global__ __launch_bounds__(256) void fused_kernel(
    const int* __restrict__ x,
    const f32x4* __restrict__ mu,
    const f32x4* __restrict__ rho,
    const f32x4* __restrict__ eps,
    f32x4* __restrict__ out,
    int n_rows)
{
    int tid  = blockIdx.x * blockDim.x + threadIdx.x;
    int row  = tid >> 5;
    int lane = tid & 31;
    if (row >= n_rows) return;
    long src = (long)x[row] * D4 + lane;
    f32x4 m = mu[src], r = rho[src], e = eps[src];
    f32x4 o;
    o.x = m.x + softplus_f(r.x) * clip10(e.x);
    o.y = m.y + softplus_f(r.y) * clip10(e.y);
    o.z = m.z + softplus_f(r.z) * clip10(e.z);
    o.w = m.w + softplus_f(r.w) * clip10(e.w);
    out[(long)row * D4 + lane] = o;
}

extern "C" void kernel_launch(void* const* d_in, const int* in_sizes, int n_in,
                              void* d_out, int out_size, void* d_ws, size_t ws_size,
                              hipStream_t stream)
{
    const int*   x   = (const int*)  d_in[0];
    const f32x4* mu  = (const f32x4*)d_in[1];
    const f32x4* rho = (const f32x4*)d_in[2];
    const f32x4* eps = (const f32x4*)d_in[3];

    int  n_rows      = in_sizes[0];        // B*L
    long table_elems = (long)in_sizes[1];  // V*D
    int  V           = (int)(table_elems / 128);   // D = 128
    size_t table_bytes_bf16 = (size_t)table_elems * sizeof(u16);
    const int block = 256;

    if (ws_size >= table_bytes_bf16) {
        long n4 = table_elems / 4;

        long threads1 = (n4 + 1) / 2;                         // 2 float4 per thread
        int grid1 = (int)((threads1 + block - 1) / block);
        sample_table_bf16_kernel<<<grid1, block, 0, stream>>>(
            mu, rho, eps, (u16x4*)d_ws, n4);

        int vslice = (V + NXCD - 1) / NXCD;                   // 12500
        int chunk  = 1024;                                    // rows per block
        int nchunks = (n_rows + chunk - 1) / chunk;           // 800
        int grid2 = nchunks * NXCD;                           // 6400 blocks
        gather_sliced_kernel<<<grid2, block, 0, stream>>>(
            x, (const u32*)d_ws, (f32x2*)d_out, n_rows, vslice, chunk);
    } else {
        long threads = (long)n_rows * 32;
        int grid = (int)((threads + block - 1) / block);
        fused_kernel<<<grid, block, 0, stream>>>(x, mu, rho, eps, (f32x4*)d_out, n_rows);
    }
}

// Round 10
// 139.106 us; speedup vs baseline: 1.0857x; 1.0027x over previous
//
#include <hip/hip_runtime.h>
#include <hip/hip_bf16.h>

typedef float f32x2 __attribute__((ext_vector_type(2)));
typedef float f32x4 __attribute__((ext_vector_type(4)));
typedef unsigned short u16;
typedef unsigned int   u32;
typedef u16 u16x4 __attribute__((ext_vector_type(4)));
typedef u16 u16x8 __attribute__((ext_vector_type(8)));

#define D4  32   // D=128 floats = 32 float4 per row
#define NXCD 8

__device__ __forceinline__ float softplus_f(float r) {
    return (r > 20.0f) ? r : __logf(1.0f + __expf(r));
}
__device__ __forceinline__ float clip10(float e) {
    return fminf(fmaxf(e, -10.0f), 10.0f);
}
__device__ __forceinline__ u16 f32_to_bf16_rne(float f) {
    u32 b = __float_as_uint(f);
    b += 0x7FFFu + ((b >> 16) & 1u);   // round-to-nearest-even
    return (u16)(b >> 16);
}
__device__ __forceinline__ float bf16_to_f32(u16 h) {
    return __uint_as_float(((u32)h) << 16);
}

// Pass 1: tab[i] = bf16( mu[i] + softplus(rho[i]) * clip(eps[i]) ), 8 elems/thread.
__global__ __launch_bounds__(256) void sample_table_bf16_kernel(
    const f32x4* __restrict__ mu,
    const f32x4* __restrict__ rho,
    const f32x4* __restrict__ eps,
    u16x4* __restrict__ tab,
    long n4)
{
    long t  = (long)blockIdx.x * blockDim.x + threadIdx.x;
    long j0 = t * 2, j1 = j0 + 1;
    if (j0 >= n4) return;

    f32x4 m0 = __builtin_nontemporal_load(&mu[j0]);
    f32x4 r0 = __builtin_nontemporal_load(&rho[j0]);
    f32x4 e0 = __builtin_nontemporal_load(&eps[j0]);

    u16x4 o0;
    o0.x = f32_to_bf16_rne(m0.x + softplus_f(r0.x) * clip10(e0.x));
    o0.y = f32_to_bf16_rne(m0.y + softplus_f(r0.y) * clip10(e0.y));
    o0.z = f32_to_bf16_rne(m0.z + softplus_f(r0.z) * clip10(e0.z));
    o0.w = f32_to_bf16_rne(m0.w + softplus_f(r0.w) * clip10(e0.w));

    if (j1 < n4) {
        f32x4 m1 = __builtin_nontemporal_load(&mu[j1]);
        f32x4 r1 = __builtin_nontemporal_load(&rho[j1]);
        f32x4 e1 = __builtin_nontemporal_load(&eps[j1]);
        u16x8 o;
        o[0] = o0.x; o[1] = o0.y; o[2] = o0.z; o[3] = o0.w;
        o[4] = f32_to_bf16_rne(m1.x + softplus_f(r1.x) * clip10(e1.x));
        o[5] = f32_to_bf16_rne(m1.y + softplus_f(r1.y) * clip10(e1.y));
        o[6] = f32_to_bf16_rne(m1.z + softplus_f(r1.z) * clip10(e1.z));
        o[7] = f32_to_bf16_rne(m1.w + softplus_f(r1.w) * clip10(e1.w));
        *(u16x8*)&tab[j0] = o;           // one 16 B store
    } else {
        tab[j0] = o0;
    }
}

// Pass 2, XCD-sliced: blockIdx%8 selects a vocab slice (12500 rows = 3.2 MB,
// fits one XCD's 4 MB L2; blockIdx%8 round-robins to XCDs). Each block scans
// a chunk of x with a 64-lane ballot and gathers only rows in its slice, so
// each table row crosses the fabric once and then hits the local L2.
// Row read: 64 lanes x 4 B (u32 = 2 bf16) = 256 B = one bf16 row.
// Row write: 64 lanes x 8 B (f32x2) = 512 B contiguous, nontemporal.
__global__ __launch_bounds__(256) void gather_sliced_kernel(
    const int* __restrict__ x,
    const u32* __restrict__ tab,   // bf16 table viewed as u32 pairs: 64 per row
    f32x2* __restrict__ out,       // f32 rows: 64 f32x2 per row
    int n_rows, int vslice, int chunk)
{
    int bucket  = blockIdx.x & (NXCD - 1);
    int chunkid = blockIdx.x >> 3;
    int lo = bucket * vslice;
    int hi = lo + vslice;

    long base = (long)chunkid * chunk;
    long end  = base + chunk;
    if (end > n_rows) end = n_rows;

    int wid  = threadIdx.x >> 6;   // 4 waves per block
    int lane = threadIdx.x & 63;

    for (long r = base + (long)wid * 64; r < end; r += 256) {
        long rr = r + lane;
        int  v  = (rr < end) ? x[rr] : -1;
        bool mine = (v >= lo) & (v < hi);
        unsigned long long mask = __ballot(mine);
        while (mask) {
            int bit = __ffsll((long long)mask) - 1;
            mask &= mask - 1;
            int  vv   = __shfl(v, bit);     // vocab row (wave-uniform)
            long orow = r + bit;            // output row
            u32 w = tab[(long)vv * 64 + lane];   // L2-resident slice
            f32x2 f;
            f.x = bf16_to_f32((u16)(w & 0xffffu));
            f.y = bf16_to_f32((u16)(w >> 16));
            __builtin_nontemporal_store(f, &out[orow * 64 + lane]);
        }
    }
}

// Fallback (ws too small): fused f32 kernel.
__global__ __launch_bounds__(256) void fused_kernel(
    const int* __restrict__ x,
    const f32x4* __restrict__ mu,
    const f32x4* __restrict__ rho,
    const f32x4* __restrict__ eps,
    f32x4* __restrict__ out,
    int n_rows)
{
    int tid  = blockIdx.x * blockDim.x + threadIdx.x;
    int row  = tid >> 5;
    int lane = tid & 31;
    if (row >= n_rows) return;
    long src = (long)x[row] * D4 + lane;
    f32x4 m = mu[src], r = rho[src], e = eps[src];
    f32x4 o;
    o.x = m.x + softplus_f(r.x) * clip10(e.x);
    o.y = m.y + softplus_f(r.y) * clip10(e.y);
    o.z = m.z + softplus_f(r.z) * clip10(e.z);
    o.w = m.w + softplus_f(r.w) * clip10(e.w);
    out[(long)row * D4 + lane] = o;
}

extern "C" void kernel_launch(void* const* d_in, const int* in_sizes, int n_in,
                              void* d_out, int out_size, void* d_ws, size_t ws_size,
                              hipStream_t stream)
{
    const int*   x   = (const int*)  d_in[0];
    const f32x4* mu  = (const f32x4*)d_in[1];
    const f32x4* rho = (const f32x4*)d_in[2];
    const f32x4* eps = (const f32x4*)d_in[3];

    int  n_rows      = in_sizes[0];        // B*L
    long table_elems = (long)in_sizes[1];  // V*D
    int  V           = (int)(table_elems / 128);   // D = 128
    size_t table_bytes_bf16 = (size_t)table_elems * sizeof(u16);
    const int block = 256;

    if (ws_size >= table_bytes_bf16) {
        long n4 = table_elems / 4;

        long threads1 = (n4 + 1) / 2;                         // 2 float4 per thread
        int grid1 = (int)((threads1 + block - 1) / block);
        sample_table_bf16_kernel<<<grid1, block, 0, stream>>>(
            mu, rho, eps, (u16x4*)d_ws, n4);

        int vslice = (V + NXCD - 1) / NXCD;                   // 12500
        int chunk  = 1024;                                    // rows per block
        int nchunks = (n_rows + chunk - 1) / chunk;           // 800
        int grid2 = nchunks * NXCD;                           // 6400 blocks
        gather_sliced_kernel<<<grid2, block, 0, stream>>>(
            x, (const u32*)d_ws, (f32x2*)d_out, n_rows, vslice, chunk);
    } else {
        long threads = (long)n_rows * 32;
        int grid = (int)((threads + block - 1) / block);
        fused_kernel<<<grid, block, 0, stream>>>(x, mu, rho, eps, (f32x4*)d_out, n_rows);
    }
}